// Round 7
// baseline (472.983 us; speedup 1.0000x reference)
//
#include <hip/hip_runtime.h>
#include <cstddef>
#include <cstdint>

// Problem: B=2, S=2048, E=1024, H=16, D=64.  Softmax over HEADS (ref quirk).
#define BATCH 2
#define S_LEN 2048
#define E_DIM 1024
#define NH    16
#define HD    64
#define M_ROWS (BATCH * S_LEN)   // 4096

typedef unsigned short u16;
typedef short  bf16x8 __attribute__((ext_vector_type(8)));
typedef float  f32x4  __attribute__((ext_vector_type(4)));

__device__ __forceinline__ u16 f2bf(float f) {
    union { float f; unsigned u; } v; v.f = f;
    unsigned r = v.u + 0x7fffu + ((v.u >> 16) & 1u);   // RNE
    return (u16)(r >> 16);
}
__device__ __forceinline__ float bf2f(u16 h) {
    union { unsigned u; float f; } v; v.u = ((unsigned)h) << 16;
    return v.f;
}

// async global->LDS DMA, 16 B per lane (global_load_lds_dwordx4).
__device__ __forceinline__ void load_lds16(const u16* g, u16* l) {
    __builtin_amdgcn_global_load_lds(
        (const __attribute__((address_space(1))) unsigned int*)g,
        (__attribute__((address_space(3))) unsigned int*)l, 16, 0, 0);
}

// ---------------------------------------------------------------------------
// fp32 -> bf16 bulk convert (n % 4 == 0)
// ---------------------------------------------------------------------------
__global__ void cvt_bf16(const float* __restrict__ in, u16* __restrict__ out, int n)
{
    int i = (blockIdx.x * 256 + threadIdx.x) * 4;
    if (i + 3 < n) {
        float4 v = *(const float4*)(in + i);
        u16 o[4] = { f2bf(v.x), f2bf(v.y), f2bf(v.z), f2bf(v.w) };
        *(uint2*)(out + i) = *(const uint2*)o;
    }
}

// ---------------------------------------------------------------------------
// ctx = p0+p1+p2+p3 (bf16 in, fp32 add, bf16 out)
// ---------------------------------------------------------------------------
__global__ void combine4(const u16* __restrict__ p0, const u16* __restrict__ p1,
                         const u16* __restrict__ p2, const u16* __restrict__ p3,
                         u16* __restrict__ c, int n)
{
    int i = (blockIdx.x * 256 + threadIdx.x) * 4;
    if (i + 3 < n) {
        uint2 u0 = *(const uint2*)(p0 + i);
        uint2 u1 = *(const uint2*)(p1 + i);
        uint2 u2 = *(const uint2*)(p2 + i);
        uint2 u3 = *(const uint2*)(p3 + i);
        const u16* a = (const u16*)&u0; const u16* b = (const u16*)&u1;
        const u16* d = (const u16*)&u2; const u16* e = (const u16*)&u3;
        u16 o[4];
#pragma unroll
        for (int j = 0; j < 4; ++j)
            o[j] = f2bf((bf2f(a[j]) + bf2f(b[j])) + (bf2f(d[j]) + bf2f(e[j])));
        *(uint2*)(c + i) = *(const uint2*)o;
    }
}

// ---------------------------------------------------------------------------
// Fused QKV projection GEMM (m97-style DMA staging).   [verified R6]
// ---------------------------------------------------------------------------
__global__ __launch_bounds__(256)
void gemm_qkv(const u16* __restrict__ A, const u16* __restrict__ W3,
              const float* __restrict__ bq, const float* __restrict__ bk,
              const float* __restrict__ bv,
              u16* __restrict__ Qb, u16* __restrict__ Kb, u16* __restrict__ Vtb)
{
    __shared__ u16 Al[128 * 32];
    __shared__ u16 Bl[128 * 32];
    const int K = E_DIM;
    const int t = threadIdx.x;
    const int w = t >> 6, lane = t & 63;
    const int quad = lane >> 4, lm = lane & 15;
    const int wy = w >> 1, wx = w & 1;
    const int m0 = blockIdx.x * 128, n0 = blockIdx.y * 128;
    const int lrow  = lane >> 2;
    const int lcol8 = (lane & 3) * 8;

    f32x4 acc[4][4] = {};

    for (int kb = 0; kb < K; kb += 32) {
        __syncthreads();
#pragma unroll
        for (int i = 0; i < 2; ++i) {
            const int r0 = w * 32 + i * 16;
            load_lds16(A  + (size_t)(m0 + r0 + lrow) * K + kb + lcol8, &Al[r0 * 32]);
            load_lds16(W3 + (size_t)(n0 + r0 + lrow) * K + kb + lcol8, &Bl[r0 * 32]);
        }
        __syncthreads();

        bf16x8 af[4], bfr[4];
#pragma unroll
        for (int i = 0; i < 4; ++i)
            af[i] = *(const bf16x8*)(Al + (wy * 64 + i * 16 + lm) * 32 + quad * 8);
#pragma unroll
        for (int j = 0; j < 4; ++j)
            bfr[j] = *(const bf16x8*)(Bl + (wx * 64 + j * 16 + lm) * 32 + quad * 8);
#pragma unroll
        for (int i = 0; i < 4; ++i)
#pragma unroll
            for (int j = 0; j < 4; ++j)
                acc[i][j] = __builtin_amdgcn_mfma_f32_16x16x32_bf16(af[i], bfr[j], acc[i][j], 0, 0, 0);
    }

    const int seg = n0 >> 10;            // 0=Q, 1=K, 2=V
    const int nl0 = n0 & 1023;
    const float* bs = (seg == 0) ? bq : (seg == 1) ? bk : bv;

    if (seg < 2) {
        u16* dst = (seg == 0) ? Qb : Kb;
#pragma unroll
        for (int j = 0; j < 4; ++j) {
            const int n = nl0 + wx * 64 + j * 16 + lm;
            const float bias = bs[n];
#pragma unroll
            for (int i = 0; i < 4; ++i) {
                const int mrow = m0 + wy * 64 + i * 16 + quad * 4;
#pragma unroll
                for (int rg = 0; rg < 4; ++rg)
                    dst[(size_t)(mrow + rg) * E_DIM + n] = f2bf(acc[i][j][rg] + bias);
            }
        }
    } else {
#pragma unroll
        for (int j = 0; j < 4; ++j) {
            const int n = nl0 + wx * 64 + j * 16 + lm;
            const float bias = bs[n];
#pragma unroll
            for (int i = 0; i < 4; ++i) {
                const int mrow = m0 + wy * 64 + i * 16 + quad * 4;
                const int batch = mrow >> 11;
                const int sloc  = mrow & 2047;
                u16 o[4];
#pragma unroll
                for (int rg = 0; rg < 4; ++rg) o[rg] = f2bf(acc[i][j][rg] + bias);
                *(uint2*)&Vtb[(size_t)batch * E_DIM * S_LEN + (size_t)n * S_LEN + sloc]
                    = *(const uint2*)o;
            }
        }
    }
}

// ---------------------------------------------------------------------------
// Output projection GEMM (DMA-staged), fp32 out.   [verified R6]
// ---------------------------------------------------------------------------
__global__ __launch_bounds__(256)
void gemm_wo(const u16* __restrict__ A, const u16* __restrict__ B,
             const float* __restrict__ bias, float* __restrict__ C)
{
    __shared__ u16 Al[128 * 32];
    __shared__ u16 Bl[128 * 32];
    const int K = E_DIM, N = E_DIM;
    const int t = threadIdx.x;
    const int w = t >> 6, lane = t & 63;
    const int quad = lane >> 4, lm = lane & 15;
    const int wy = w >> 1, wx = w & 1;
    const int m0 = blockIdx.x * 128, n0 = blockIdx.y * 128;
    const int lrow  = lane >> 2;
    const int lcol8 = (lane & 3) * 8;

    f32x4 acc[4][4] = {};

    for (int kb = 0; kb < K; kb += 32) {
        __syncthreads();
#pragma unroll
        for (int i = 0; i < 2; ++i) {
            const int r0 = w * 32 + i * 16;
            load_lds16(A + (size_t)(m0 + r0 + lrow) * K + kb + lcol8, &Al[r0 * 32]);
            load_lds16(B + (size_t)(n0 + r0 + lrow) * K + kb + lcol8, &Bl[r0 * 32]);
        }
        __syncthreads();

        bf16x8 af[4], bfr[4];
#pragma unroll
        for (int i = 0; i < 4; ++i)
            af[i] = *(const bf16x8*)(Al + (wy * 64 + i * 16 + lm) * 32 + quad * 8);
#pragma unroll
        for (int j = 0; j < 4; ++j)
            bfr[j] = *(const bf16x8*)(Bl + (wx * 64 + j * 16 + lm) * 32 + quad * 8);
#pragma unroll
        for (int i = 0; i < 4; ++i)
#pragma unroll
            for (int j = 0; j < 4; ++j)
                acc[i][j] = __builtin_amdgcn_mfma_f32_16x16x32_bf16(af[i], bfr[j], acc[i][j], 0, 0, 0);
    }

#pragma unroll
    for (int j = 0; j < 4; ++j) {
        const int n = n0 + wx * 64 + j * 16 + lm;
        const float bs = bias[n];
#pragma unroll
        for (int i = 0; i < 4; ++i) {
            const int mrow = m0 + wy * 64 + i * 16 + quad * 4;
#pragma unroll
            for (int rg = 0; rg < 4; ++rg)
                C[(size_t)(mrow + rg) * N + n] = acc[i][j][rg] + bs;
        }
    }
}

// ---------------------------------------------------------------------------
// attn_v6 = attn_v3 structure (verified 289 us) + occupancy fix:
//   - scores stored bf16 pre-scaled (Sb 32->16 KB)  => LDS 48->32 KB
//   - KSPLIT 2->4  => grid 1024 = 4 blocks/CU resident (16 waves/CU, was 8)
//   - __launch_bounds__(256,4) caps VGPR at 128 (was 84)
// Everything else byte-identical to v3.
// ---------------------------------------------------------------------------
__global__ __launch_bounds__(256, 4)
void attn_v6(const u16* __restrict__ Q, const u16* __restrict__ K,
             const u16* __restrict__ Vt,
             u16* __restrict__ c0, u16* __restrict__ c1,
             u16* __restrict__ c2, u16* __restrict__ c3)
{
    __shared__ u16 smem[2 * NH * 16 * 32];   // 32 KB total
    u16* Sb = smem;                 // [h][q][k] bf16 scores (pre-scaled)
    u16* Pb = smem + NH * 16 * 32;  // [h][q][k] bf16 weights

    const int t    = threadIdx.x;
    const int w    = t >> 6, lane = t & 63;
    const int quad = lane >> 4, lm = lane & 15;
    const int ks   = blockIdx.x & 3;
    const int qt   = (blockIdx.x >> 2) & 127;
    const int b    = blockIdx.x >> 9;
    const int q0   = qt * 16;

    const size_t qbase = ((size_t)b * S_LEN + q0) * E_DIM;
    const size_t kmat  = (size_t)b * S_LEN * E_DIM;
    const size_t vtb   = (size_t)b * E_DIM * S_LEN;

    bf16x8 qf[4][2];
#pragma unroll
    for (int h2 = 0; h2 < 4; ++h2)
#pragma unroll
        for (int hf = 0; hf < 2; ++hf)
            qf[h2][hf] = *(const bf16x8*)(Q + qbase + (size_t)lm * E_DIM
                                          + (w * 4 + h2) * 64 + hf * 32 + quad * 8);

    f32x4 acc[4][4] = {};   // [h2][dtile]

    const int kbeg = ks * (S_LEN / 4);   // 512-key span

    for (int c = 0; c < (S_LEN / 4) / 32; ++c) {
        const int k0 = kbeg + c * 32;

        // ---- QK^T: scores for this wave's 4 heads (bf16, pre-scaled) ----
#pragma unroll
        for (int h2 = 0; h2 < 4; ++h2) {
            const int h = w * 4 + h2;
#pragma unroll
            for (int kt2 = 0; kt2 < 2; ++kt2) {
                f32x4 sf = {};
#pragma unroll
                for (int hf = 0; hf < 2; ++hf) {
                    bf16x8 kf = *(const bf16x8*)(K + kmat
                                 + (size_t)(k0 + kt2 * 16 + lm) * E_DIM
                                 + h * 64 + hf * 32 + quad * 8);
                    sf = __builtin_amdgcn_mfma_f32_16x16x32_bf16(qf[h2][hf], kf, sf, 0, 0, 0);
                }
#pragma unroll
                for (int rg = 0; rg < 4; ++rg)
                    Sb[h * 512 + (quad * 4 + rg) * 32 + kt2 * 16 + lm]
                        = f2bf(sf[rg] * 0.125f);     // 1/sqrt(64) folded here
            }
        }
        __syncthreads();

        // ---- wide softmax over heads: 2 (q,k) pairs per thread ----
#pragma unroll
        for (int p = 0; p < 2; ++p) {
            const int idx = p * 256 + t;
            const int qq = idx >> 5, kk = idx & 31;
            float sv[16]; float mx = -1e30f;
#pragma unroll
            for (int h = 0; h < 16; ++h) {
                sv[h] = bf2f(Sb[h * 512 + qq * 32 + kk]);
                mx = fmaxf(mx, sv[h]);
            }
            float sum = 0.f;
#pragma unroll
            for (int h = 0; h < 16; ++h) {
                sv[h] = __expf(sv[h] - mx);
                sum += sv[h];
            }
            const float inv = 1.f / sum;
#pragma unroll
            for (int h = 0; h < 16; ++h)
                Pb[h * 512 + qq * 32 + kk] = f2bf(sv[h] * inv);
        }
        __syncthreads();

        // ---- PV: ctx[q][d] += P[q,keys] * Vt[d,keys] ----
#pragma unroll
        for (int h2 = 0; h2 < 4; ++h2) {
            const int h = w * 4 + h2;
            bf16x8 pf = *(const bf16x8*)(Pb + h * 512 + lm * 32 + quad * 8);
#pragma unroll
            for (int dt = 0; dt < 4; ++dt) {
                bf16x8 vf = *(const bf16x8*)(Vt + vtb
                             + (size_t)(h * 64 + dt * 16 + lm) * S_LEN
                             + k0 + quad * 8);
                acc[h2][dt] = __builtin_amdgcn_mfma_f32_16x16x32_bf16(pf, vf, acc[h2][dt], 0, 0, 0);
            }
        }
    }

    __syncthreads();
    // ---- epilogue: stage 16q x 1024e bf16 tile in LDS (= full 32 KB) ----
    u16* Ol = smem;
#pragma unroll
    for (int h2 = 0; h2 < 4; ++h2) {
        const int h = w * 4 + h2;
#pragma unroll
        for (int dt = 0; dt < 4; ++dt)
#pragma unroll
            for (int rg = 0; rg < 4; ++rg)
                Ol[(quad * 4 + rg) * 1024 + h * 64 + dt * 16 + lm] = f2bf(acc[h2][dt][rg]);
    }
    __syncthreads();
    u16* dst = (ks == 0) ? c0 : (ks == 1) ? c1 : (ks == 2) ? c2 : c3;
#pragma unroll
    for (int i = 0; i < 8; ++i) {
        const int unit = i * 256 + t;
        const int r = unit >> 7, cu = unit & 127;
        *(bf16x8*)(dst + ((size_t)b * S_LEN + q0 + r) * E_DIM + cu * 8) =
            *(const bf16x8*)(Ol + r * 1024 + cu * 8);
    }
}

// ---------------------------------------------------------------------------
extern "C" void kernel_launch(void* const* d_in, const int* in_sizes, int n_in,
                              void* d_out, int out_size, void* d_ws, size_t ws_size,
                              hipStream_t stream)
{
    const float* x  = (const float*)d_in[0];
    const float* Wq = (const float*)d_in[1];
    const float* bq = (const float*)d_in[2];
    const float* Wk = (const float*)d_in[3];
    const float* bk = (const float*)d_in[4];
    const float* Wv = (const float*)d_in[5];
    const float* bv = (const float*)d_in[6];
    const float* Wo = (const float*)d_in[7];
    const float* bo = (const float*)d_in[8];
    float* out = (float*)d_out;

    // bf16 workspace (u16 elems), 72 MB:
    const size_t MAT = (size_t)M_ROWS * E_DIM;   // 4M elems
    const size_t WSZ = (size_t)E_DIM * E_DIM;    // 1M elems
    u16* xb   = (u16*)d_ws;          // x; later combined ctx
    u16* W3   = xb   + MAT;          // Wq|Wk|Wv concat [3072][1024]
    u16* Wob  = W3   + 3 * WSZ;
    u16* Qb   = Wob  + WSZ;
    u16* Kb   = Qb   + MAT;
    u16* Vtb  = Kb   + MAT;          // V transposed [b][e][s]
    u16* ctx0 = Vtb  + MAT;
    u16* ctx1 = ctx0 + MAT;
    u16* ctx2 = ctx1 + MAT;
    u16* ctx3 = ctx2 + MAT;

    // 1) convert inputs to bf16 (weights into concat buffer)
    cvt_bf16<<<(int)(MAT / 1024), 256, 0, stream>>>(x,  xb, (int)MAT);
    cvt_bf16<<<(int)(WSZ / 1024), 256, 0, stream>>>(Wq, W3,           (int)WSZ);
    cvt_bf16<<<(int)(WSZ / 1024), 256, 0, stream>>>(Wk, W3 + WSZ,     (int)WSZ);
    cvt_bf16<<<(int)(WSZ / 1024), 256, 0, stream>>>(Wv, W3 + 2 * WSZ, (int)WSZ);
    cvt_bf16<<<(int)(WSZ / 1024), 256, 0, stream>>>(Wo, Wob,          (int)WSZ);

    // 2) fused QKV projection (writes Qb, Kb, Vtb-transposed)
    dim3 qkvgrid(M_ROWS / 128, 3 * E_DIM / 128);   // 32 x 24 = 768 blocks
    gemm_qkv<<<qkvgrid, 256, 0, stream>>>(xb, W3, bq, bk, bv, Qb, Kb, Vtb);

    // 3) fused MFMA attention, KSPLIT=4, 4 blocks/CU resident
    attn_v6<<<BATCH * 128 * 4, 256, 0, stream>>>(Qb, Kb, Vtb, ctx0, ctx1, ctx2, ctx3);

    // 4) combine k-quarters into xb (x is dead)
    combine4<<<(int)(MAT / 1024), 256, 0, stream>>>(ctx0, ctx1, ctx2, ctx3, xb, (int)MAT);

    // 5) output projection (fp32 out)
    dim3 ogrid(M_ROWS / 128, E_DIM / 128);         // 32 x 8
    gemm_wo<<<ogrid, 256, 0, stream>>>(xb, Wob, bo, out);
}

// Round 8
// 468.251 us; speedup vs baseline: 1.0101x; 1.0101x over previous
//
#include <hip/hip_runtime.h>
#include <cstddef>
#include <cstdint>

// Problem: B=2, S=2048, E=1024, H=16, D=64.  Softmax over HEADS (ref quirk).
#define BATCH 2
#define S_LEN 2048
#define E_DIM 1024
#define NH    16
#define HD    64
#define M_ROWS (BATCH * S_LEN)   // 4096

typedef unsigned short u16;
typedef short  bf16x8 __attribute__((ext_vector_type(8)));
typedef float  f32x4  __attribute__((ext_vector_type(4)));

__device__ __forceinline__ u16 f2bf(float f) {
    union { float f; unsigned u; } v; v.f = f;
    unsigned r = v.u + 0x7fffu + ((v.u >> 16) & 1u);   // RNE
    return (u16)(r >> 16);
}
__device__ __forceinline__ float bf2f(u16 h) {
    union { unsigned u; float f; } v; v.u = ((unsigned)h) << 16;
    return v.f;
}

// async global->LDS DMA, 16 B per lane (global_load_lds_dwordx4).
__device__ __forceinline__ void load_lds16(const u16* g, u16* l) {
    __builtin_amdgcn_global_load_lds(
        (const __attribute__((address_space(1))) unsigned int*)g,
        (__attribute__((address_space(3))) unsigned int*)l, 16, 0, 0);
}

// ---------------------------------------------------------------------------
// fp32 -> bf16 bulk convert (n % 4 == 0)
// ---------------------------------------------------------------------------
__global__ void cvt_bf16(const float* __restrict__ in, u16* __restrict__ out, int n)
{
    int i = (blockIdx.x * 256 + threadIdx.x) * 4;
    if (i + 3 < n) {
        float4 v = *(const float4*)(in + i);
        u16 o[4] = { f2bf(v.x), f2bf(v.y), f2bf(v.z), f2bf(v.w) };
        *(uint2*)(out + i) = *(const uint2*)o;
    }
}

// ---------------------------------------------------------------------------
// ctx = p0+p1+p2+p3 (bf16 in, fp32 add, bf16 out)
// ---------------------------------------------------------------------------
__global__ void combine4(const u16* __restrict__ p0, const u16* __restrict__ p1,
                         const u16* __restrict__ p2, const u16* __restrict__ p3,
                         u16* __restrict__ c, int n)
{
    int i = (blockIdx.x * 256 + threadIdx.x) * 4;
    if (i + 3 < n) {
        uint2 u0 = *(const uint2*)(p0 + i);
        uint2 u1 = *(const uint2*)(p1 + i);
        uint2 u2 = *(const uint2*)(p2 + i);
        uint2 u3 = *(const uint2*)(p3 + i);
        const u16* a = (const u16*)&u0; const u16* b = (const u16*)&u1;
        const u16* d = (const u16*)&u2; const u16* e = (const u16*)&u3;
        u16 o[4];
#pragma unroll
        for (int j = 0; j < 4; ++j)
            o[j] = f2bf((bf2f(a[j]) + bf2f(b[j])) + (bf2f(d[j]) + bf2f(e[j])));
        *(uint2*)(c + i) = *(const uint2*)o;
    }
}

// ---------------------------------------------------------------------------
// Fused QKV projection GEMM (m97-style DMA staging).   [verified R6]
// ---------------------------------------------------------------------------
__global__ __launch_bounds__(256)
void gemm_qkv(const u16* __restrict__ A, const u16* __restrict__ W3,
              const float* __restrict__ bq, const float* __restrict__ bk,
              const float* __restrict__ bv,
              u16* __restrict__ Qb, u16* __restrict__ Kb, u16* __restrict__ Vtb)
{
    __shared__ u16 Al[128 * 32];
    __shared__ u16 Bl[128 * 32];
    const int K = E_DIM;
    const int t = threadIdx.x;
    const int w = t >> 6, lane = t & 63;
    const int quad = lane >> 4, lm = lane & 15;
    const int wy = w >> 1, wx = w & 1;
    const int m0 = blockIdx.x * 128, n0 = blockIdx.y * 128;
    const int lrow  = lane >> 2;
    const int lcol8 = (lane & 3) * 8;

    f32x4 acc[4][4] = {};

    for (int kb = 0; kb < K; kb += 32) {
        __syncthreads();
#pragma unroll
        for (int i = 0; i < 2; ++i) {
            const int r0 = w * 32 + i * 16;
            load_lds16(A  + (size_t)(m0 + r0 + lrow) * K + kb + lcol8, &Al[r0 * 32]);
            load_lds16(W3 + (size_t)(n0 + r0 + lrow) * K + kb + lcol8, &Bl[r0 * 32]);
        }
        __syncthreads();

        bf16x8 af[4], bfr[4];
#pragma unroll
        for (int i = 0; i < 4; ++i)
            af[i] = *(const bf16x8*)(Al + (wy * 64 + i * 16 + lm) * 32 + quad * 8);
#pragma unroll
        for (int j = 0; j < 4; ++j)
            bfr[j] = *(const bf16x8*)(Bl + (wx * 64 + j * 16 + lm) * 32 + quad * 8);
#pragma unroll
        for (int i = 0; i < 4; ++i)
#pragma unroll
            for (int j = 0; j < 4; ++j)
                acc[i][j] = __builtin_amdgcn_mfma_f32_16x16x32_bf16(af[i], bfr[j], acc[i][j], 0, 0, 0);
    }

    const int seg = n0 >> 10;            // 0=Q, 1=K, 2=V
    const int nl0 = n0 & 1023;
    const float* bs = (seg == 0) ? bq : (seg == 1) ? bk : bv;

    if (seg < 2) {
        u16* dst = (seg == 0) ? Qb : Kb;
#pragma unroll
        for (int j = 0; j < 4; ++j) {
            const int n = nl0 + wx * 64 + j * 16 + lm;
            const float bias = bs[n];
#pragma unroll
            for (int i = 0; i < 4; ++i) {
                const int mrow = m0 + wy * 64 + i * 16 + quad * 4;
#pragma unroll
                for (int rg = 0; rg < 4; ++rg)
                    dst[(size_t)(mrow + rg) * E_DIM + n] = f2bf(acc[i][j][rg] + bias);
            }
        }
    } else {
#pragma unroll
        for (int j = 0; j < 4; ++j) {
            const int n = nl0 + wx * 64 + j * 16 + lm;
            const float bias = bs[n];
#pragma unroll
            for (int i = 0; i < 4; ++i) {
                const int mrow = m0 + wy * 64 + i * 16 + quad * 4;
                const int batch = mrow >> 11;
                const int sloc  = mrow & 2047;
                u16 o[4];
#pragma unroll
                for (int rg = 0; rg < 4; ++rg) o[rg] = f2bf(acc[i][j][rg] + bias);
                *(uint2*)&Vtb[(size_t)batch * E_DIM * S_LEN + (size_t)n * S_LEN + sloc]
                    = *(const uint2*)o;
            }
        }
    }
}

// ---------------------------------------------------------------------------
// Output projection GEMM (DMA-staged), fp32 out.   [verified R6]
// ---------------------------------------------------------------------------
__global__ __launch_bounds__(256)
void gemm_wo(const u16* __restrict__ A, const u16* __restrict__ B,
             const float* __restrict__ bias, float* __restrict__ C)
{
    __shared__ u16 Al[128 * 32];
    __shared__ u16 Bl[128 * 32];
    const int K = E_DIM, N = E_DIM;
    const int t = threadIdx.x;
    const int w = t >> 6, lane = t & 63;
    const int quad = lane >> 4, lm = lane & 15;
    const int wy = w >> 1, wx = w & 1;
    const int m0 = blockIdx.x * 128, n0 = blockIdx.y * 128;
    const int lrow  = lane >> 2;
    const int lcol8 = (lane & 3) * 8;

    f32x4 acc[4][4] = {};

    for (int kb = 0; kb < K; kb += 32) {
        __syncthreads();
#pragma unroll
        for (int i = 0; i < 2; ++i) {
            const int r0 = w * 32 + i * 16;
            load_lds16(A + (size_t)(m0 + r0 + lrow) * K + kb + lcol8, &Al[r0 * 32]);
            load_lds16(B + (size_t)(n0 + r0 + lrow) * K + kb + lcol8, &Bl[r0 * 32]);
        }
        __syncthreads();

        bf16x8 af[4], bfr[4];
#pragma unroll
        for (int i = 0; i < 4; ++i)
            af[i] = *(const bf16x8*)(Al + (wy * 64 + i * 16 + lm) * 32 + quad * 8);
#pragma unroll
        for (int j = 0; j < 4; ++j)
            bfr[j] = *(const bf16x8*)(Bl + (wx * 64 + j * 16 + lm) * 32 + quad * 8);
#pragma unroll
        for (int i = 0; i < 4; ++i)
#pragma unroll
            for (int j = 0; j < 4; ++j)
                acc[i][j] = __builtin_amdgcn_mfma_f32_16x16x32_bf16(af[i], bfr[j], acc[i][j], 0, 0, 0);
    }

#pragma unroll
    for (int j = 0; j < 4; ++j) {
        const int n = n0 + wx * 64 + j * 16 + lm;
        const float bs = bias[n];
#pragma unroll
        for (int i = 0; i < 4; ++i) {
            const int mrow = m0 + wy * 64 + i * 16 + quad * 4;
#pragma unroll
            for (int rg = 0; rg < 4; ++rg)
                C[(size_t)(mrow + rg) * N + n] = acc[i][j][rg] + bs;
        }
    }
}

// ---------------------------------------------------------------------------
// attn_v6b = attn_v3 structure + bf16 Sb (LDS 32 KB) + KSPLIT=4, but with
// __launch_bounds__(256, 2): natural VGPR alloc (~84) stays <= 128, so HW
// residency = min(LDS 160/32=5, VGPR 4 waves/SIMD, grid 4) = 4 blocks/CU
// WITHOUT forcing the allocator into spills (R7's mistake: min-waves=4
// forced VGPR=64 -> scratch spills -> FETCH 297 MB, regression).
// ---------------------------------------------------------------------------
__global__ __launch_bounds__(256, 2)
void attn_v6b(const u16* __restrict__ Q, const u16* __restrict__ K,
              const u16* __restrict__ Vt,
              u16* __restrict__ c0, u16* __restrict__ c1,
              u16* __restrict__ c2, u16* __restrict__ c3)
{
    __shared__ u16 smem[2 * NH * 16 * 32];   // 32 KB total
    u16* Sb = smem;                 // [h][q][k] bf16 scores (pre-scaled)
    u16* Pb = smem + NH * 16 * 32;  // [h][q][k] bf16 weights

    const int t    = threadIdx.x;
    const int w    = t >> 6, lane = t & 63;
    const int quad = lane >> 4, lm = lane & 15;
    const int ks   = blockIdx.x & 3;
    const int qt   = (blockIdx.x >> 2) & 127;
    const int b    = blockIdx.x >> 9;
    const int q0   = qt * 16;

    const size_t qbase = ((size_t)b * S_LEN + q0) * E_DIM;
    const size_t kmat  = (size_t)b * S_LEN * E_DIM;
    const size_t vtb   = (size_t)b * E_DIM * S_LEN;

    bf16x8 qf[4][2];
#pragma unroll
    for (int h2 = 0; h2 < 4; ++h2)
#pragma unroll
        for (int hf = 0; hf < 2; ++hf)
            qf[h2][hf] = *(const bf16x8*)(Q + qbase + (size_t)lm * E_DIM
                                          + (w * 4 + h2) * 64 + hf * 32 + quad * 8);

    f32x4 acc[4][4] = {};   // [h2][dtile]

    const int kbeg = ks * (S_LEN / 4);   // 512-key span

    for (int c = 0; c < (S_LEN / 4) / 32; ++c) {
        const int k0 = kbeg + c * 32;

        // ---- QK^T: scores for this wave's 4 heads (bf16, pre-scaled) ----
#pragma unroll
        for (int h2 = 0; h2 < 4; ++h2) {
            const int h = w * 4 + h2;
#pragma unroll
            for (int kt2 = 0; kt2 < 2; ++kt2) {
                f32x4 sf = {};
#pragma unroll
                for (int hf = 0; hf < 2; ++hf) {
                    bf16x8 kf = *(const bf16x8*)(K + kmat
                                 + (size_t)(k0 + kt2 * 16 + lm) * E_DIM
                                 + h * 64 + hf * 32 + quad * 8);
                    sf = __builtin_amdgcn_mfma_f32_16x16x32_bf16(qf[h2][hf], kf, sf, 0, 0, 0);
                }
#pragma unroll
                for (int rg = 0; rg < 4; ++rg)
                    Sb[h * 512 + (quad * 4 + rg) * 32 + kt2 * 16 + lm]
                        = f2bf(sf[rg] * 0.125f);     // 1/sqrt(64) folded here
            }
        }
        __syncthreads();

        // ---- wide softmax over heads: 2 (q,k) pairs per thread ----
#pragma unroll
        for (int p = 0; p < 2; ++p) {
            const int idx = p * 256 + t;
            const int qq = idx >> 5, kk = idx & 31;
            float sv[16]; float mx = -1e30f;
#pragma unroll
            for (int h = 0; h < 16; ++h) {
                sv[h] = bf2f(Sb[h * 512 + qq * 32 + kk]);
                mx = fmaxf(mx, sv[h]);
            }
            float sum = 0.f;
#pragma unroll
            for (int h = 0; h < 16; ++h) {
                sv[h] = __expf(sv[h] - mx);
                sum += sv[h];
            }
            const float inv = 1.f / sum;
#pragma unroll
            for (int h = 0; h < 16; ++h)
                Pb[h * 512 + qq * 32 + kk] = f2bf(sv[h] * inv);
        }
        __syncthreads();

        // ---- PV: ctx[q][d] += P[q,keys] * Vt[d,keys] ----
#pragma unroll
        for (int h2 = 0; h2 < 4; ++h2) {
            const int h = w * 4 + h2;
            bf16x8 pf = *(const bf16x8*)(Pb + h * 512 + lm * 32 + quad * 8);
#pragma unroll
            for (int dt = 0; dt < 4; ++dt) {
                bf16x8 vf = *(const bf16x8*)(Vt + vtb
                             + (size_t)(h * 64 + dt * 16 + lm) * S_LEN
                             + k0 + quad * 8);
                acc[h2][dt] = __builtin_amdgcn_mfma_f32_16x16x32_bf16(pf, vf, acc[h2][dt], 0, 0, 0);
            }
        }
    }

    __syncthreads();
    // ---- epilogue: stage 16q x 1024e bf16 tile in LDS (= full 32 KB) ----
    u16* Ol = smem;
#pragma unroll
    for (int h2 = 0; h2 < 4; ++h2) {
        const int h = w * 4 + h2;
#pragma unroll
        for (int dt = 0; dt < 4; ++dt)
#pragma unroll
            for (int rg = 0; rg < 4; ++rg)
                Ol[(quad * 4 + rg) * 1024 + h * 64 + dt * 16 + lm] = f2bf(acc[h2][dt][rg]);
    }
    __syncthreads();
    u16* dst = (ks == 0) ? c0 : (ks == 1) ? c1 : (ks == 2) ? c2 : c3;
#pragma unroll
    for (int i = 0; i < 8; ++i) {
        const int unit = i * 256 + t;
        const int r = unit >> 7, cu = unit & 127;
        *(bf16x8*)(dst + ((size_t)b * S_LEN + q0 + r) * E_DIM + cu * 8) =
            *(const bf16x8*)(Ol + r * 1024 + cu * 8);
    }
}

// ---------------------------------------------------------------------------
extern "C" void kernel_launch(void* const* d_in, const int* in_sizes, int n_in,
                              void* d_out, int out_size, void* d_ws, size_t ws_size,
                              hipStream_t stream)
{
    const float* x  = (const float*)d_in[0];
    const float* Wq = (const float*)d_in[1];
    const float* bq = (const float*)d_in[2];
    const float* Wk = (const float*)d_in[3];
    const float* bk = (const float*)d_in[4];
    const float* Wv = (const float*)d_in[5];
    const float* bv = (const float*)d_in[6];
    const float* Wo = (const float*)d_in[7];
    const float* bo = (const float*)d_in[8];
    float* out = (float*)d_out;

    // bf16 workspace (u16 elems), 72 MB:
    const size_t MAT = (size_t)M_ROWS * E_DIM;   // 4M elems
    const size_t WSZ = (size_t)E_DIM * E_DIM;    // 1M elems
    u16* xb   = (u16*)d_ws;          // x; later combined ctx
    u16* W3   = xb   + MAT;          // Wq|Wk|Wv concat [3072][1024]
    u16* Wob  = W3   + 3 * WSZ;
    u16* Qb   = Wob  + WSZ;
    u16* Kb   = Qb   + MAT;
    u16* Vtb  = Kb   + MAT;          // V transposed [b][e][s]
    u16* ctx0 = Vtb  + MAT;
    u16* ctx1 = ctx0 + MAT;
    u16* ctx2 = ctx1 + MAT;
    u16* ctx3 = ctx2 + MAT;

    // 1) convert inputs to bf16 (weights into concat buffer)
    cvt_bf16<<<(int)(MAT / 1024), 256, 0, stream>>>(x,  xb, (int)MAT);
    cvt_bf16<<<(int)(WSZ / 1024), 256, 0, stream>>>(Wq, W3,           (int)WSZ);
    cvt_bf16<<<(int)(WSZ / 1024), 256, 0, stream>>>(Wk, W3 + WSZ,     (int)WSZ);
    cvt_bf16<<<(int)(WSZ / 1024), 256, 0, stream>>>(Wv, W3 + 2 * WSZ, (int)WSZ);
    cvt_bf16<<<(int)(WSZ / 1024), 256, 0, stream>>>(Wo, Wob,          (int)WSZ);

    // 2) fused QKV projection (writes Qb, Kb, Vtb-transposed)
    dim3 qkvgrid(M_ROWS / 128, 3 * E_DIM / 128);   // 32 x 24 = 768 blocks
    gemm_qkv<<<qkvgrid, 256, 0, stream>>>(xb, W3, bq, bk, bv, Qb, Kb, Vtb);

    // 3) fused MFMA attention, KSPLIT=4, spill-free 4 blocks/CU
    attn_v6b<<<BATCH * 128 * 4, 256, 0, stream>>>(Qb, Kb, Vtb, ctx0, ctx1, ctx2, ctx3);

    // 4) combine k-quarters into xb (x is dead)
    combine4<<<(int)(MAT / 1024), 256, 0, stream>>>(ctx0, ctx1, ctx2, ctx3, xb, (int)MAT);

    // 5) output projection (fp32 out)
    dim3 ogrid(M_ROWS / 128, E_DIM / 128);         // 32 x 8
    gemm_wo<<<ogrid, 256, 0, stream>>>(xb, Wob, bo, out);
}